// Round 1
// baseline (1022.347 us; speedup 1.0000x reference)
//
#include <hip/hip_runtime.h>
#include <hip/hip_fp16.h>

#define TPB 512

// LDS layout (bytes):
//   K (f16, swizzled)  [0, 131072)
//   red (8x256 f32)    [131072, 139264)
//   a,b,u,v (256 f32)  [139264, 143360)
//   scr (32 f32)       [143360, 143488)
#define SHMEM_BYTES 143488

__global__ __launch_bounds__(TPB, 2) void sinkhorn_kernel(
    const float* __restrict__ cost,
    const float* __restrict__ mass_pred,
    const float* __restrict__ mass_target,
    float* __restrict__ out)
{
    extern __shared__ char smem[];
    __half* Ksh  = (__half*)smem;                      // 256 rows x 256 cols f16, swizzled
    float*  red  = (float*)(smem + 131072);            // 8 waves x 256 partials
    float*  a_sh = (float*)(smem + 131072 + 8192);
    float*  b_sh = a_sh + 256;
    float*  u_sh = b_sh + 256;
    float*  v_sh = u_sh + 256;
    float*  scr  = v_sh + 256;

    const int t    = threadIdx.x;
    const int bat  = blockIdx.x;
    const int lane = t & 63;
    const int wv   = t >> 6;   // 8 waves

    //---------------- Phase 0: normalize masses, init u,v ----------------
    float vmp = 0.f, vmt = 0.f;
    if (t < 256) {
        vmp = mass_pred [bat * 256 + t];
        vmt = mass_target[bat * 256 + t];
    }
    float s1 = vmp, s2 = vmt;
    #pragma unroll
    for (int o = 32; o > 0; o >>= 1) {
        s1 += __shfl_xor(s1, o);
        s2 += __shfl_xor(s2, o);
    }
    if (lane == 0) { scr[wv] = s1; scr[8 + wv] = s2; }
    __syncthreads();
    if (t == 0) {
        float ta = 0.f, tb = 0.f;
        #pragma unroll
        for (int w = 0; w < 8; ++w) { ta += scr[w]; tb += scr[8 + w]; }
        scr[16] = ta + 1e-8f;
        scr[17] = tb + 1e-8f;
    }
    __syncthreads();
    if (t < 256) {
        a_sh[t] = vmp / scr[16];
        b_sh[t] = vmt / scr[17];
        u_sh[t] = 1.0f;
        v_sh[t] = 1.0f;
    }

    //---------------- Phase 1: K = exp(-C/eps) -> f16 swizzled LDS --------
    // Swizzle: row n, logical 16B-block blk (8 halfs) stored at phys = blk ^ (n&31)
    {
        const float4* C4 = (const float4*)(cost + (size_t)bat * 65536);
        #pragma unroll 4
        for (int i = 0; i < 32; ++i) {
            int idx = i * TPB + t;        // float4 index; row n = idx>>6, m = 4*(idx&63)
            float4 c = C4[idx];
            int n  = idx >> 6;
            int l  = idx & 63;
            int blk = (l >> 1) ^ (n & 31);
            int hlf = l & 1;
            __half2 h01 = __floats2half2_rn(__expf(c.x * -10.0f), __expf(c.y * -10.0f));
            __half2 h23 = __floats2half2_rn(__expf(c.z * -10.0f), __expf(c.w * -10.0f));
            uint2 w;
            w.x = *(unsigned int*)&h01;
            w.y = *(unsigned int*)&h23;
            *(uint2*)((char*)Ksh + n * 512 + blk * 16 + hlf * 8) = w;
        }
    }
    __syncthreads();

    //---------------- Cache Pass-A slice in registers ---------------------
    // Thread t: logical col block jA (8 cols), rows [16*rA, 16*rA+16)
    const int jA = t & 31;
    const int rA = t >> 5;      // 0..15
    uint4 kregs[16];
    #pragma unroll
    for (int i = 0; i < 16; ++i) {
        int n = 16 * rA + i;
        int phys = jA ^ (n & 31);
        kregs[i] = *(const uint4*)((const char*)Ksh + n * 512 + phys * 16);
    }

    const int pB  = t & 31;     // Pass B: rows {pB + 32k}
    const int cbB = t >> 5;     // Pass B: cols [16*cbB, 16*cbB+16)

    //---------------- Phase 2: 100 Sinkhorn iterations --------------------
    for (int it = 0; it < 100; ++it) {
        // ---- Pass A: Ktu[m] = sum_n K[n][m]*u[n];  v = b/(Ktu+eps)
        float uu[16];
        {
            const float4* up = (const float4*)(u_sh + 16 * rA);
            #pragma unroll
            for (int q = 0; q < 4; ++q) ((float4*)uu)[q] = up[q];
        }
        float acc[8];
        #pragma unroll
        for (int q = 0; q < 8; ++q) acc[q] = 0.f;
        #pragma unroll
        for (int i = 0; i < 16; ++i) {
            const __half2* hp = (const __half2*)&kregs[i];
            float un = uu[i];
            #pragma unroll
            for (int q = 0; q < 4; ++q) {
                float2 f = __half22float2(hp[q]);
                acc[2*q]   = fmaf(f.x, un, acc[2*q]);
                acc[2*q+1] = fmaf(f.y, un, acc[2*q+1]);
            }
        }
        #pragma unroll
        for (int q = 0; q < 8; ++q) acc[q] += __shfl_xor(acc[q], 32);
        if (lane < 32) {
            float* dst = red + wv * 256 + jA * 8;
            ((float4*)dst)[0] = make_float4(acc[0], acc[1], acc[2], acc[3]);
            ((float4*)dst)[1] = make_float4(acc[4], acc[5], acc[6], acc[7]);
        }
        __syncthreads();
        if (t < 256) {
            float s = 1e-8f;
            #pragma unroll
            for (int w = 0; w < 8; ++w) s += red[w * 256 + t];
            v_sh[t] = b_sh[t] / s;
        }
        __syncthreads();

        // ---- Pass B: Kv[n] = sum_m K[n][m]*v[m];  u = a/(Kv+eps)
        float vv[16];
        {
            const float4* vp = (const float4*)(v_sh + 16 * cbB);
            #pragma unroll
            for (int q = 0; q < 4; ++q) ((float4*)vv)[q] = vp[q];
        }
        float accb[8];
        #pragma unroll
        for (int rk = 0; rk < 8; ++rk) {
            int n = pB + 32 * rk;
            float s = 0.f;
            #pragma unroll
            for (int jj = 0; jj < 2; ++jj) {
                int phys = (2 * cbB + jj) ^ pB;   // n&31 == pB
                uint4 kk = *(const uint4*)((const char*)Ksh + n * 512 + phys * 16);
                const __half2* hp = (const __half2*)&kk;
                #pragma unroll
                for (int q = 0; q < 4; ++q) {
                    float2 f = __half22float2(hp[q]);
                    s = fmaf(f.x, vv[jj*8 + 2*q],     s);
                    s = fmaf(f.y, vv[jj*8 + 2*q + 1], s);
                }
            }
            accb[rk] = s;
        }
        #pragma unroll
        for (int rk = 0; rk < 8; ++rk) accb[rk] += __shfl_xor(accb[rk], 32);
        if (lane < 32) {
            #pragma unroll
            for (int rk = 0; rk < 8; ++rk)
                red[wv * 256 + rk * 32 + pB] = accb[rk];   // rk*32+pB == n
        }
        __syncthreads();
        if (t < 256) {
            float s = 1e-8f;
            #pragma unroll
            for (int w = 0; w < 8; ++w) s += red[w * 256 + t];
            u_sh[t] = a_sh[t] / s;
        }
        __syncthreads();
    }

    //---------------- Phase 3: ot_cost = sum u K v * C,  C = -eps*log(K) --
    float uq[16];
    {
        const float4* up = (const float4*)(u_sh + 16 * rA);
        #pragma unroll
        for (int q = 0; q < 4; ++q) ((float4*)uq)[q] = up[q];
    }
    float vv8[8];
    {
        const float4* vp = (const float4*)(v_sh + 8 * jA);
        ((float4*)vv8)[0] = vp[0];
        ((float4*)vv8)[1] = vp[1];
    }
    float s = 0.f;
    #pragma unroll
    for (int i = 0; i < 16; ++i) {
        const __half2* hp = (const __half2*)&kregs[i];
        float un = uq[i];
        #pragma unroll
        for (int q = 0; q < 4; ++q) {
            float2 f = __half22float2(hp[q]);
            float c0 = -0.1f * __logf(f.x);
            float c1 = -0.1f * __logf(f.y);
            s = fmaf(un * f.x * c0, vv8[2*q],     s);
            s = fmaf(un * f.y * c1, vv8[2*q + 1], s);
        }
    }
    #pragma unroll
    for (int o = 32; o > 0; o >>= 1) s += __shfl_xor(s, o);
    if (lane == 0) scr[wv] = s;
    __syncthreads();
    if (t == 0) {
        float tot = 0.f;
        #pragma unroll
        for (int w = 0; w < 8; ++w) tot += scr[w];
        atomicAdd(out, tot * (1.0f / 1024.0f));
    }
}

extern "C" void kernel_launch(void* const* d_in, const int* in_sizes, int n_in,
                              void* d_out, int out_size, void* d_ws, size_t ws_size,
                              hipStream_t stream) {
    const float* cost = (const float*)d_in[0];
    const float* mp   = (const float*)d_in[1];
    const float* mt   = (const float*)d_in[2];
    float* out = (float*)d_out;

    // out is re-poisoned to 0xAA before every timed launch -> zero it
    hipMemsetAsync(out, 0, sizeof(float), stream);

    // >64KB dynamic LDS: opt in (gfx950 has 160KB/CU)
    hipFuncSetAttribute((const void*)sinkhorn_kernel,
                        hipFuncAttributeMaxDynamicSharedMemorySize, SHMEM_BYTES);

    sinkhorn_kernel<<<1024, TPB, SHMEM_BYTES, stream>>>(cost, mp, mt, out);
}

// Round 2
// 866.733 us; speedup vs baseline: 1.1795x; 1.1795x over previous
//
#include <hip/hip_runtime.h>
#include <hip/hip_fp16.h>

#define TPB 512

// LDS layout (bytes):
//   Ksh f16 row-major 256x256   [0, 131072)   (staging + one-time extraction only)
//   u2  half2[128]              [131072, 131584)
//   v2  half2[128]              [131584, 132096)
//   a_sh f32[256]               [132096, 133120)
//   b_sh f32[256]               [133120, 134144)
//   scr  f32[32]                [134144, 134272)
#define SMEM_BYTES 134272

typedef _Float16 h2 __attribute__((ext_vector_type(2)));

union HU { unsigned u; h2 h; _Float16 s[2]; };
union QU { uint4 v; h2 h[4]; _Float16 s[8]; };

static __device__ __forceinline__ float dot2(h2 a, h2 b, float c) {
#if defined(__has_builtin)
#if __has_builtin(__builtin_amdgcn_fdot2)
    return __builtin_amdgcn_fdot2(a, b, c, false);
#else
    return fmaf((float)a.x, (float)b.x, fmaf((float)a.y, (float)b.y, c));
#endif
#else
    return fmaf((float)a.x, (float)b.x, fmaf((float)a.y, (float)b.y, c));
#endif
}

// In-wave reduce of 8 accumulators across the 16-lane group (lane bits 0..3).
// Returns the full 16-lane sum of acc[idx] where idx = 4*bit0(q)+2*bit1(q)+bit2(q),
// and writes that owned index to *own_idx.
static __device__ __forceinline__ float reduce16x8(float acc[8], int q, int* own_idx) {
    const int s0 = q & 1;
    float b4[4];
#pragma unroll
    for (int j = 0; j < 4; ++j) {
        float keep = s0 ? acc[4 + j] : acc[j];
        float send = s0 ? acc[j] : acc[4 + j];
        b4[j] = keep + __shfl_xor(send, 1);
    }
    const int s1 = (q >> 1) & 1;
    float b2[2];
#pragma unroll
    for (int j = 0; j < 2; ++j) {
        float keep = s1 ? b4[2 + j] : b4[j];
        float send = s1 ? b4[j] : b4[2 + j];
        b2[j] = keep + __shfl_xor(send, 2);
    }
    const int s2 = (q >> 2) & 1;
    {
        float keep = s2 ? b2[1] : b2[0];
        float send = s2 ? b2[0] : b2[1];
        float b1 = keep + __shfl_xor(send, 4);
        b1 += __shfl_xor(b1, 8);
        *own_idx = s0 * 4 + s1 * 2 + s2;
        return b1;
    }
}

__global__ __launch_bounds__(TPB, 2) void sinkhorn_kernel(
    const float* __restrict__ cost,
    const float* __restrict__ mass_pred,
    const float* __restrict__ mass_target,
    float* __restrict__ out)
{
    extern __shared__ char smem[];
    _Float16* Ksh = (_Float16*)smem;                 // 256 x 256, row-major
    unsigned* u2  = (unsigned*)(smem + 131072);      // 128 half2 (row pairs of u)
    unsigned* v2  = (unsigned*)(smem + 131584);      // 128 half2 (col pairs of v)
    float* a_sh   = (float*)(smem + 132096);
    float* b_sh   = (float*)(smem + 133120);
    float* scr    = (float*)(smem + 134144);

    const int t   = threadIdx.x;
    const int bat = blockIdx.x;
    const int l   = t & 63;
    const int w   = t >> 6;       // wave 0..7
    const int q   = l & 15;       // 16-lane group position (reduction axis)
    const int g   = l >> 4;       // group 0..3 within wave
    const int jA  = 4 * w + g;    // pass-A col-block (8 cols) == pass-B row-block (8 rows)

    //---------------- Phase 0: normalize masses, init u ----------------
    float vmp = 0.f, vmt = 0.f;
    if (t < 256) {
        vmp = mass_pred [bat * 256 + t];
        vmt = mass_target[bat * 256 + t];
    }
    float s1 = vmp, s2 = vmt;
#pragma unroll
    for (int o = 32; o > 0; o >>= 1) {
        s1 += __shfl_xor(s1, o);
        s2 += __shfl_xor(s2, o);
    }
    if (l == 0) { scr[w] = s1; scr[8 + w] = s2; }
    if (t < 128) {
        HU one; one.h = (h2){(_Float16)1.f, (_Float16)1.f};
        u2[t] = one.u;
    }
    __syncthreads();
    if (t == 0) {
        float ta = 0.f, tb = 0.f;
#pragma unroll
        for (int ww = 0; ww < 8; ++ww) { ta += scr[ww]; tb += scr[8 + ww]; }
        scr[16] = ta + 1e-8f;
        scr[17] = tb + 1e-8f;
    }
    __syncthreads();
    if (t < 256) {
        a_sh[t] = vmp / scr[16];
        b_sh[t] = vmt / scr[17];
    }

    //---------------- Phase 1: K = exp(-C/eps) -> f16 row-major LDS ------
    {
        const float4* C4 = (const float4*)(cost + (size_t)bat * 65536);
#pragma unroll 4
        for (int i = 0; i < 32; ++i) {
            int idx = i * TPB + t;       // float4 index: row = idx>>6, col4 = idx&63
            float4 c = C4[idx];
            int n = idx >> 6, col4 = idx & 63;
            HU p01, p23;
            p01.h = (h2){(_Float16)__expf(c.x * -10.0f), (_Float16)__expf(c.y * -10.0f)};
            p23.h = (h2){(_Float16)__expf(c.z * -10.0f), (_Float16)__expf(c.w * -10.0f)};
            *(uint2*)((char*)Ksh + n * 512 + col4 * 8) = make_uint2(p01.u, p23.u);
        }
    }
    __syncthreads();

    //---------------- One-time extraction into registers -----------------
    // A-slice (pass A, K^T u): rows [16q,16q+16), cols [8jA,8jA+8),
    //   packed along rows: apk[p][c] = (K[16q+2p][8jA+c], K[16q+2p+1][8jA+c])
    h2 apk[8][8];
#pragma unroll
    for (int p = 0; p < 8; ++p) {
        QU r0, r1;
        r0.v = *(const uint4*)((const char*)Ksh + (16 * q + 2 * p) * 512 + jA * 16);
        r1.v = *(const uint4*)((const char*)Ksh + (16 * q + 2 * p + 1) * 512 + jA * 16);
#pragma unroll
        for (int c = 0; c < 8; ++c)
            apk[p][c] = (h2){r0.s[c], r1.s[c]};
    }
    // B-slice (pass B, K v): rows [8jA,8jA+8), cols [16q,16q+16),
    //   naturally packed along cols: bpk[i][c] = (K[8jA+i][16q+2c], K[8jA+i][16q+2c+1])
    h2 bpk[8][8];
#pragma unroll
    for (int i = 0; i < 8; ++i) {
        QU s0r, s1r;
        s0r.v = *(const uint4*)((const char*)Ksh + (8 * jA + i) * 512 + q * 32);
        s1r.v = *(const uint4*)((const char*)Ksh + (8 * jA + i) * 512 + q * 32 + 16);
#pragma unroll
        for (int c = 0; c < 4; ++c) { bpk[i][c] = s0r.h[c]; bpk[i][4 + c] = s1r.h[c]; }
    }
    __syncthreads();

    //---------------- Phase 2: 100 Sinkhorn iterations --------------------
    for (int it = 0; it < 100; ++it) {
        // ---- Pass A: Ktu[m] = sum_n K[n][m] u[n];  v = b/(Ktu+eps)
        QU ua0, ua1;
        ua0.v = *(const uint4*)(u2 + 8 * q);
        ua1.v = *(const uint4*)(u2 + 8 * q + 4);
        float acc[8];
#pragma unroll
        for (int c = 0; c < 8; ++c) acc[c] = 0.f;
#pragma unroll
        for (int p = 0; p < 4; ++p) {
#pragma unroll
            for (int c = 0; c < 8; ++c) {
                acc[c] = dot2(apk[p][c], ua0.h[p], acc[c]);
                acc[c] = dot2(apk[4 + p][c], ua1.h[p], acc[c]);
            }
        }
        int idx;
        float ktu = reduce16x8(acc, q, &idx);
        {
            int col = 8 * jA + idx;
            float vv = b_sh[col] * __builtin_amdgcn_rcpf(ktu + 1e-8f);
            float vp = __shfl_xor(vv, 4);          // partner holds idx^1
            HU hv;
            hv.h = (q & 4) ? (h2){(_Float16)vp, (_Float16)vv}
                           : (h2){(_Float16)vv, (_Float16)vp};
            if (q < 4) v2[4 * jA + (idx >> 1)] = hv.u;
        }
        __syncthreads();

        // ---- Pass B: Kv[n] = sum_m K[n][m] v[m];  u = a/(Kv+eps)
        QU vb0, vb1;
        vb0.v = *(const uint4*)(v2 + 8 * q);
        vb1.v = *(const uint4*)(v2 + 8 * q + 4);
        float accb[8];
#pragma unroll
        for (int i = 0; i < 8; ++i) accb[i] = 0.f;
#pragma unroll
        for (int i = 0; i < 8; ++i) {
#pragma unroll
            for (int c = 0; c < 4; ++c) {
                accb[i] = dot2(bpk[i][c], vb0.h[c], accb[i]);
                accb[i] = dot2(bpk[i][4 + c], vb1.h[c], accb[i]);
            }
        }
        int idxb;
        float kv = reduce16x8(accb, q, &idxb);
        {
            int row = 8 * jA + idxb;
            float uu = a_sh[row] * __builtin_amdgcn_rcpf(kv + 1e-8f);
            float up = __shfl_xor(uu, 4);
            HU hu;
            hu.h = (q & 4) ? (h2){(_Float16)up, (_Float16)uu}
                           : (h2){(_Float16)uu, (_Float16)up};
            if (q < 4) u2[4 * jA + (idxb >> 1)] = hu.u;
        }
        __syncthreads();
    }

    //---------------- Phase 3: cost = sum u K v C, C = -eps log K ---------
    float s = 0.f;
    {
        QU uu0, uu1, vv0;
        uu0.v = *(const uint4*)(u2 + 8 * q);       // u rows [16q, 16q+16) as pairs
        uu1.v = *(const uint4*)(u2 + 8 * q + 4);
        vv0.v = *(const uint4*)(v2 + 4 * jA);      // v cols [8jA, 8jA+8) as pairs
        float vcol[8];
#pragma unroll
        for (int c = 0; c < 4; ++c) {
            vcol[2 * c]     = (float)vv0.h[c].x;
            vcol[2 * c + 1] = (float)vv0.h[c].y;
        }
#pragma unroll
        for (int p = 0; p < 8; ++p) {
            h2 up2 = (p < 4) ? uu0.h[p] : uu1.h[p - 4];
            float u0 = (float)up2.x, u1 = (float)up2.y;
#pragma unroll
            for (int c = 0; c < 8; ++c) {
                float k0 = (float)apk[p][c].x;
                float k1 = (float)apk[p][c].y;
                float c0 = -0.1f * __logf(k0);
                float c1 = -0.1f * __logf(k1);
                s = fmaf(u0 * k0 * c0, vcol[c], s);
                s = fmaf(u1 * k1 * c1, vcol[c], s);
            }
        }
    }
#pragma unroll
    for (int o = 32; o > 0; o >>= 1) s += __shfl_xor(s, o);
    if (l == 0) scr[w] = s;
    __syncthreads();
    if (t == 0) {
        float tot = 0.f;
#pragma unroll
        for (int ww = 0; ww < 8; ++ww) tot += scr[ww];
        atomicAdd(out, tot * (1.0f / 1024.0f));
    }
}

extern "C" void kernel_launch(void* const* d_in, const int* in_sizes, int n_in,
                              void* d_out, int out_size, void* d_ws, size_t ws_size,
                              hipStream_t stream) {
    const float* cost = (const float*)d_in[0];
    const float* mp   = (const float*)d_in[1];
    const float* mt   = (const float*)d_in[2];
    float* out = (float*)d_out;

    // out is re-poisoned to 0xAA before every timed launch -> zero it
    hipMemsetAsync(out, 0, sizeof(float), stream);

    // >64KB dynamic LDS: opt in (gfx950 has 160KB/CU)
    hipFuncSetAttribute((const void*)sinkhorn_kernel,
                        hipFuncAttributeMaxDynamicSharedMemorySize, SMEM_BYTES);

    sinkhorn_kernel<<<1024, TPB, SMEM_BYTES, stream>>>(cost, mp, mt, out);
}